// Round 2
// baseline (538.559 us; speedup 1.0000x reference)
//
#include <hip/hip_runtime.h>

typedef unsigned short u16;
typedef unsigned int u32;
typedef __attribute__((ext_vector_type(8))) __bf16 bf16x8;
typedef __attribute__((ext_vector_type(8))) unsigned short ushort8;
typedef __attribute__((ext_vector_type(4))) float f32x4;

// Exact RNE fp32 -> bf16 (no NaN inputs here). Exact for values with <=8 mantissa bits.
__device__ __forceinline__ u16 f32_to_bf16(float f) {
  u32 u = __float_as_uint(f);
  u = (u + 0x7fffu + ((u >> 16) & 1u)) >> 16;
  return (u16)u;
}

// ---------------- x: fp32 -> bf16, 8 elems/thread ----------------
__global__ void cvt_x_bf16(const float* __restrict__ x, u16* __restrict__ o, long n8) {
  long i = (long)blockIdx.x * blockDim.x + threadIdx.x;
  if (i >= n8) return;
  const float4* p = (const float4*)x + i * 2;
  float4 a = p[0], b = p[1];
  ushort8 v;
  v[0] = f32_to_bf16(a.x); v[1] = f32_to_bf16(a.y);
  v[2] = f32_to_bf16(a.z); v[3] = f32_to_bf16(a.w);
  v[4] = f32_to_bf16(b.x); v[5] = f32_to_bf16(b.y);
  v[6] = f32_to_bf16(b.z); v[7] = f32_to_bf16(b.w);
  *(ushort8*)(o + i * 8) = v;
}

// ---------------- weight dequant: w' = q_e2m1(wb/sb) * q_e4m3(ratio) ----------------
// w_dq = w' * gscale; gscale folded into GEMM epilogue. w' is EXACT in bf16
// (<=2 sig bits * <=4 sig bits = <=6 sig bits). One thread per 16-elem block.
__global__ void dequant_w(const float* __restrict__ w, const float* __restrict__ pba,
                          const float* __restrict__ gp, u16* __restrict__ wq, int nblk) {
  int i = blockIdx.x * blockDim.x + threadIdx.x;
  if (i >= nblk) return;
  float g = *gp;
  float gscale = g / 2688.0f;                   // global_amax / (6*448), fp32 like ref
  float ratio = (pba[i] / 6.0f) / gscale;       // = blk_scale_f / gscale
  ratio = fminf(fmaxf(ratio, 0.0f), 448.0f);    // ref clips to E4M3_MAX
  // e4m3 RNE quant: e = clip(floor(log2 ax), -6, 8) via exact bit-exponent
  int e = (int)((__float_as_uint(ratio) >> 23) & 0xffu) - 127;
  if (e < -6) e = -6;                           // ax<=448 => e<=8 already
  float stp = __uint_as_float((u32)(e - 3 + 127) << 23);  // 2^(e-3), exact
  float e4 = rintf(ratio / stp) * stp;          // q_e4m3 value (RNE, exact pow2 scaling)
  float sb = e4 * gscale;                       // ref blk_scale
  float den = fmaxf(sb, 1e-30f);
  bool pos = sb > 0.0f;

  const float4* wp = (const float4*)(w + (size_t)i * 16);
  float vals[16];
#pragma unroll
  for (int t = 0; t < 4; ++t) {
    float4 v = wp[t];
    vals[4 * t + 0] = v.x; vals[4 * t + 1] = v.y;
    vals[4 * t + 2] = v.z; vals[4 * t + 3] = v.w;
  }
  ushort8 o0, o1;
#pragma unroll
  for (int k = 0; k < 16; ++k) {
    float wv = pos ? vals[k] / den : 0.0f;      // true IEEE div, matches ref
    float s = (wv < 0.0f) ? -1.0f : 1.0f;
    float ax = fminf(fabsf(wv), 6.0f);          // clip to E2M1_MAX
    // e2m1 grid: half-step h = 2^clip(floor(log2 ax),0,2) / 2
    float h = ax < 2.0f ? 0.5f : (ax < 4.0f ? 1.0f : 2.0f);
    float q = rintf(ax / h) * h;                // RNE on the e2m1 grid
    u16 r = f32_to_bf16(s * q * e4);            // exact in bf16
    if (k < 8) o0[k] = r; else o1[k - 8] = r;
  }
  ushort8* dst = (ushort8*)(wq + (size_t)i * 16);
  dst[0] = o0; dst[1] = o1;
}

// ---------------- GEMM: C[M,N] = gscale * A[M,K] . B[N,K]^T, bf16 -> fp32 ----------------
// 256x256 tile, BK=32, 4-deep LDS buffer ring (4 x 32KB = 128 KiB), 8 waves (2Mx4N),
// 8-phase-per-K128 schedule: per phase {ds_read frags | 1 half-tile global_load_lds |
// barrier | 16 MFMA (setprio) | barrier}. Counted vmcnt(8) once per K-tile (never 0
// in main loop). LDS granule-XOR swizzle via pre-swizzled global source (linear LDS
// dest, required by global_load_lds) + swizzled ds_read. XCD-aware block swizzle.
//
// Swizzle derivation (R1 fix): rows are 64B = 16 banks, so bank slot of a 16B
// granule is 16*(row&1) + 4*granule. The frag read is 16 consecutive rows at one
// granule q; within a same-parity subset (8 rows, stride 2) the XOR key must cycle
// through all 4 granule values -> tau(row) = (row>>1)&3 (each value hit 2x = free
// 2-way). R0's tau = row&3 took only 2 values over stride-2 rows -> 4-way conflict
// (measured 2.5e7 conflict cycles). Both sides use the same involution:
//   staging source granule  = (lane&3) ^ ((srow>>1)&3),  srow = wave*16+(lane>>2)
//   frag read granule       = (lane>>4) ^ ((row>>1)&3),  row bases == 0 mod 16
//
// Schedule safety invariants (load-index arithmetic):
//  - stage at K-tile t targets buf[(t+3)&3] = buf[(t-1)&3], last read during K-tile
//    t-1 whose ds_reads complete (compiler lgkmcnt) before its trailing barrier;
//    stage is issued after that barrier -> no overwrite-while-read.
//  - per-wave load order: prologue A0 B0 A1 B1 A2 B2 (loads 1..12); ktile t stages
//    A(t+3) = loads 4t+13,14 (ph0) and B(t+3) = 4t+15,16 (ph1). At ktile t's
//    vmcnt(8) (ph1, after issuing B(t+3)): issued = 4t+16, so loads <= 4t+8 have
//    landed = B(t+1) complete -> tile t+1 fully resident before its ph0 reads.
//    Tail: t=NK-3 -> vmcnt(4), then vmcnt(0).
#define GLL16(gp_, lp_)                                              \
  __builtin_amdgcn_global_load_lds(                                  \
      (__attribute__((address_space(1))) void*)(gp_),                \
      (__attribute__((address_space(3))) void*)(lp_), 16, 0, 0)

// phase-boundary fence: raw barrier (no vmcnt(0) drain!) pinned by sched_barrier so
// the compiler cannot move ds_reads / global_load_lds / MFMA across phases.
#define SBAR()                                   \
  do {                                           \
    __builtin_amdgcn_sched_barrier(0);           \
    __builtin_amdgcn_s_barrier();                \
    __builtin_amdgcn_sched_barrier(0);           \
  } while (0)

template <int VM, bool STG>
__device__ __forceinline__ void ktile(int t, u16 (&lds)[4][2][8192],
                                      const u16* gAs, const u16* gBs, size_t rh,
                                      int aro, int bro, int col8, int wave,
                                      f32x4 (&acc)[8][4]) {
  const u16* aL = &lds[t & 3][0][0];
  const u16* bL = &lds[t & 3][1][0];
  bf16x8 af[4], bv[4];
  // ---------------- phase 0: A-chunk prefetch, frags m0-3 + b, 16 MFMA ----------------
  if (STG) {
    u16* sd = &lds[(t + 3) & 3][0][wave * 512];
    const u16* g = gAs + (size_t)(t + 3) * 32;
    GLL16(g, sd);
    GLL16(g + rh, sd + 4096);
  }
#pragma unroll
  for (int m = 0; m < 4; ++m)
    af[m] = *(const bf16x8*)&aL[(aro + m * 16) * 32 + col8];
#pragma unroll
  for (int n = 0; n < 4; ++n)
    bv[n] = *(const bf16x8*)&bL[(bro + n * 16) * 32 + col8];
  SBAR();
  __builtin_amdgcn_s_setprio(1);
#pragma unroll
  for (int m = 0; m < 4; ++m)
#pragma unroll
    for (int n = 0; n < 4; ++n)
      acc[m][n] = __builtin_amdgcn_mfma_f32_16x16x32_bf16(af[m], bv[n], acc[m][n], 0, 0, 0);
  __builtin_amdgcn_s_setprio(0);
  SBAR();
  // ---------------- phase 1: B-chunk prefetch, frags m4-7, vmcnt, 16 MFMA -------------
  if (STG) {
    u16* sd = &lds[(t + 3) & 3][1][wave * 512];
    const u16* g = gBs + (size_t)(t + 3) * 32;
    GLL16(g, sd);
    GLL16(g + rh, sd + 4096);
  }
#pragma unroll
  for (int m = 0; m < 4; ++m)
    af[m] = *(const bf16x8*)&aL[(aro + 64 + m * 16) * 32 + col8];
  asm volatile("s_waitcnt vmcnt(%0)" ::"n"(VM) : "memory");
  SBAR();
  __builtin_amdgcn_s_setprio(1);
#pragma unroll
  for (int m = 0; m < 4; ++m)
#pragma unroll
    for (int n = 0; n < 4; ++n)
      acc[m + 4][n] =
          __builtin_amdgcn_mfma_f32_16x16x32_bf16(af[m], bv[n], acc[m + 4][n], 0, 0, 0);
  __builtin_amdgcn_s_setprio(0);
  SBAR();
}

__global__ __launch_bounds__(512, 2) void gemm_bt(
    const u16* __restrict__ A, const u16* __restrict__ B,
    float* __restrict__ C, const float* __restrict__ gp,
    int M, int N, int K) {
  __shared__ u16 lds[4][2][8192];  // 4 bufs x (A 256x32 | B 256x32) bf16 = 128 KiB
  const int tid = threadIdx.x;
  const int lane = tid & 63;
  const int wave = tid >> 6;

  // XCD-aware bijective swizzle: nwg = 512 = 8 XCDs x 64. N-major decomposition so
  // each XCD's 32 resident blocks (1 block/CU) share ONE 2MB B-panel -> L2-resident.
  const int bid = blockIdx.x;
  const int wg = (bid & 7) * 64 + (bid >> 3);
  const int bx = wg >> 5;   // 0..15 (N)
  const int by = wg & 31;   // 0..31 (M)
  const int m0 = by * 256;
  const int n0 = bx * 256;
  const int NK = K >> 5;    // 128 K-tiles of BK=32

  f32x4 zero = {0.0f, 0.0f, 0.0f, 0.0f};
  f32x4 acc[8][4];
#pragma unroll
  for (int i = 0; i < 8; ++i)
#pragma unroll
    for (int j = 0; j < 4; ++j) acc[i][j] = zero;

  const int wrow = wave >> 2;   // 0..1 : wave owns rows [wrow*128, +128)
  const int wcol = wave & 3;    // 0..3 : cols [wcol*64, +64)

  // Staging: 512 threads x 2 x 16B per 16KB chunk. Linear LDS byte
  // L = j*8192 + wave*1024 + lane*16 -> row srow = j*128 + wave*16 + (lane>>2),
  // granule g_l = lane&3. Swizzled layout: LDS granule g_l holds global granule
  // g_l ^ ((srow>>1)&3) = (lane&3) ^ ((lane>>3)&3)   (j*128, wave*16 drop out mod 8).
  const int srow = wave * 16 + (lane >> 2);
  const int scol = (((lane & 3) ^ ((lane >> 3) & 3)) << 3);
  const u16* gAs = A + (size_t)(m0 + srow) * K + scol;
  const u16* gBs = B + (size_t)(n0 + srow) * K + scol;
  const size_t rh = (size_t)128 * K;  // second 128-row half of each chunk

  // Fragment reads: lane wants global granule q=(lane>>4) of row base+(lane&15);
  // stored at LDS granule q ^ ((row>>1)&3) = (lane>>4) ^ ((lane>>1)&3)
  // (row bases wrow*128 / wcol*64 / m*16 are all 0 mod 16).
  const int aro = wrow * 128 + (lane & 15);
  const int bro = wcol * 64 + (lane & 15);
  const int col8 = (((lane >> 4) ^ ((lane >> 1) & 3)) << 3);

  // prologue: stage K-tiles 0,1,2 (chunks A0 B0 A1 B1 A2 B2 = 12 loads/wave)
#pragma unroll
  for (int t = 0; t < 3; ++t) {
    u16* dA = &lds[t][0][wave * 512];
    u16* dB = &lds[t][1][wave * 512];
    const u16* ga = gAs + (size_t)t * 32;
    const u16* gb = gBs + (size_t)t * 32;
    GLL16(ga, dA);
    GLL16(ga + rh, dA + 4096);
    GLL16(gb, dB);
    GLL16(gb + rh, dB + 4096);
  }
  // 12 issued, wait to 8 outstanding -> A0,B0 landed; barrier makes it global.
  asm volatile("s_waitcnt vmcnt(8)" ::: "memory");
  SBAR();

  int t = 0;
  for (; t < NK - 3; ++t)
    ktile<8, true>(t, lds, gAs, gBs, rh, aro, bro, col8, wave, acc);
  ktile<4, false>(t, lds, gAs, gBs, rh, aro, bro, col8, wave, acc); ++t;  // NK-3
  ktile<0, false>(t, lds, gAs, gBs, rh, aro, bro, col8, wave, acc); ++t;  // NK-2
  ktile<0, false>(t, lds, gAs, gBs, rh, aro, bro, col8, wave, acc);       // NK-1

  // epilogue: C/D layout col=lane&15, row=(lane>>4)*4+reg (m89/m91-verified)
  const float gs = (*gp) / 2688.0f;
  const int crow = m0 + wrow * 128 + ((lane >> 4) << 2);
  const int ccol = n0 + wcol * 64 + (lane & 15);
#pragma unroll
  for (int m = 0; m < 8; ++m)
#pragma unroll
    for (int r = 0; r < 4; ++r) {
      float* cp = C + (size_t)(crow + m * 16 + r) * N + ccol;
#pragma unroll
      for (int n = 0; n < 4; ++n) cp[n * 16] = acc[m][n][r] * gs;
    }
}

extern "C" void kernel_launch(void* const* d_in, const int* in_sizes, int n_in,
                              void* d_out, int out_size, void* d_ws, size_t ws_size,
                              hipStream_t stream) {
  const float* x   = (const float*)d_in[0];   // (T, I) fp32
  const float* w   = (const float*)d_in[1];   // (O, I) fp32
  const float* pba = (const float*)d_in[2];   // (O, I/16) fp32
  const float* gam = (const float*)d_in[3];   // scalar fp32
  float* out = (float*)d_out;                 // (T, O) fp32

  const int T = 8192, I = 4096, O = 4096;
  u16* xb = (u16*)d_ws;                       // T*I bf16 = 64 MB
  u16* wb = xb + (size_t)T * I;               // O*I bf16 = 32 MB

  long n8 = (long)T * I / 8;
  hipLaunchKernelGGL(cvt_x_bf16, dim3((unsigned)((n8 + 255) / 256)), dim3(256), 0, stream,
                     x, xb, n8);
  int nblk = O * (I / 16);
  hipLaunchKernelGGL(dequant_w, dim3(nblk / 256), dim3(256), 0, stream,
                     w, pba, gam, wb, nblk);
  hipLaunchKernelGGL(gemm_bt, dim3(O / 256 * (T / 256)), dim3(512), 0, stream,
                     xb, wb, out, gam, T, O, I);
}

// Round 4
// 503.606 us; speedup vs baseline: 1.0694x; 1.0694x over previous
//
#include <hip/hip_runtime.h>

typedef unsigned short u16;
typedef unsigned int u32;
typedef __attribute__((ext_vector_type(8))) __bf16 bf16x8;
typedef __attribute__((ext_vector_type(4))) unsigned short u16x4;
typedef __attribute__((ext_vector_type(4))) float f32x4;

// Exact RNE fp32 -> bf16 (no NaN inputs here). Exact for values with <=8 mantissa bits.
__device__ __forceinline__ u16 f32_to_bf16(float f) {
  u32 u = __float_as_uint(f);
  u = (u + 0x7fffu + ((u >> 16) & 1u)) >> 16;
  return (u16)u;
}

// ---------------- x: fp32 -> bf16, one float4 per thread (unit-stride 16B/lane) ----
__global__ void cvt_x_bf16(const float* __restrict__ x, u16* __restrict__ o, long n4) {
  long i = (long)blockIdx.x * blockDim.x + threadIdx.x;
  if (i >= n4) return;
  float4 a = ((const float4*)x)[i];
  u16x4 v;
  v[0] = f32_to_bf16(a.x); v[1] = f32_to_bf16(a.y);
  v[2] = f32_to_bf16(a.z); v[3] = f32_to_bf16(a.w);
  *(u16x4*)(o + i * 4) = v;
}

// ---------------- weight dequant: 4 lanes per 16-elem block (unit-stride 16B/lane) --
// Numerics identical to prior passing version; scale math recomputed redundantly x4.
__global__ void dequant_w(const float* __restrict__ w, const float* __restrict__ pba,
                          const float* __restrict__ gp, u16* __restrict__ wq, int nth) {
  int idx = blockIdx.x * blockDim.x + threadIdx.x;
  if (idx >= nth) return;
  int i = idx >> 2;                             // 16-elem block index
  float g = *gp;
  float gscale = g / 2688.0f;                   // global_amax / (6*448), fp32 like ref
  float ratio = (pba[i] / 6.0f) / gscale;       // = blk_scale_f / gscale
  ratio = fminf(fmaxf(ratio, 0.0f), 448.0f);    // ref clips to E4M3_MAX
  int e = (int)((__float_as_uint(ratio) >> 23) & 0xffu) - 127;
  if (e < -6) e = -6;                           // ax<=448 => e<=8 already
  float stp = __uint_as_float((u32)(e - 3 + 127) << 23);  // 2^(e-3), exact
  float e4 = rintf(ratio / stp) * stp;          // q_e4m3 value (RNE, exact pow2 scaling)
  float sb = e4 * gscale;                       // ref blk_scale
  float den = fmaxf(sb, 1e-30f);
  bool pos = sb > 0.0f;

  float4 v = ((const float4*)w)[idx];           // this lane's quarter of the block
  float vals[4] = {v.x, v.y, v.z, v.w};
  u16x4 o;
#pragma unroll
  for (int k = 0; k < 4; ++k) {
    float wv = pos ? vals[k] / den : 0.0f;      // true IEEE div, matches ref
    float s = (wv < 0.0f) ? -1.0f : 1.0f;
    float ax = fminf(fabsf(wv), 6.0f);          // clip to E2M1_MAX
    float h = ax < 2.0f ? 0.5f : (ax < 4.0f ? 1.0f : 2.0f);
    float q = rintf(ax / h) * h;                // RNE on the e2m1 grid
    o[k] = f32_to_bf16(s * q * e4);             // exact in bf16
  }
  *(u16x4*)(wq + (size_t)idx * 4) = o;
}

// ---------------- GEMM: C[M,N] = gscale * A[M,K] . B[N,K]^T, bf16 -> fp32 ----------------
// 256x256 tile, BK=32, 4-deep LDS ring (128 KiB), 8 waves (2Mx4N), 2 phases/K-tile.
// R2 fix: register-double-buffered fragments — ds_reads for phase p+1 are issued
// BEFORE the barrier preceding MFMA(p), so the LDS pipe serves them while the MFMA
// pipe executes phase p (previously reads+MFMA serialized: 1300 cyc/phase measured,
// = 515 MFMA + ~565 exposed LDS + barriers). lgkmcnt before MFMA(p) then only waits
// on reads issued in p-1, already served. Counted vmcnt(8) once per K-tile.
//
// Swizzle (R1, verified: conflicts -> 0): rows are 64B, bank slot of a 16B granule
// = 16*(row&1) + 4*granule; key tau(row) = (row>>1)&3 cycles all 4 granules over
// same-parity rows. Staging source granule = (lane&3)^((srow>>1)&3); frag read
// granule = (lane>>4)^((row>>1)&3). Same involution both sides (rule #21).
//
// Schedule safety (load-index arithmetic):
//  - per-wave load order: prologue A0 B0 A1 B1 A2 B2 (loads 1..12); ktile t stages
//    A(t+3) = loads 4t+13,14 (ph0), B(t+3) = 4t+15,16 (ph1). At ktile t ph1's
//    vmcnt(8): issued = 4t+16 -> loads <= 4t+8 landed = chunk B(t+1) complete ->
//    tile t+1 fully resident. The barrier AFTER vmcnt publishes this cross-wave
//    BEFORE any wave's tile-(t+1) frag reads (issued post-barrier, same phase).
//    Tail: t=NK-3 -> vmcnt(4); t=NK-2 -> vmcnt(0); t=NK-1 LAST (no reads).
//  - overwrite anti-dep: stage at ktile t targets buf[(t+3)&3] = buf[(t-1)&3].
//    Last reads of buf[(t-1)&3] (afB(t-1), issued ph0 of t-1) are lgkm-drained
//    before MFMA ph1(t-1), i.e. before the trailing barrier of ph1(t-1); the
//    overwrite is issued after that barrier -> no overwrite-while-read.
#define GLL16(gp_, lp_)                                              \
  __builtin_amdgcn_global_load_lds(                                  \
      (__attribute__((address_space(1))) void*)(gp_),                \
      (__attribute__((address_space(3))) void*)(lp_), 16, 0, 0)

#define SBAR()                                   \
  do {                                           \
    __builtin_amdgcn_sched_barrier(0);           \
    __builtin_amdgcn_s_barrier();                \
    __builtin_amdgcn_sched_barrier(0);           \
  } while (0)

template <int VM, bool STG, bool LAST>
__device__ __forceinline__ void ktile(int t, u16 (&lds)[4][2][8192],
                                      const u16* gAs, const u16* gBs, size_t rh,
                                      int aro, int bro, int col8, int wave,
                                      bf16x8 (&aC)[4], bf16x8 (&aN)[4],
                                      bf16x8 (&bC)[4], bf16x8 (&bN)[4],
                                      f32x4 (&acc)[8][4]) {
  const u16* aL = &lds[t & 3][0][0];
  const u16* aL1 = &lds[(t + 1) & 3][0][0];
  const u16* bL1 = &lds[(t + 1) & 3][1][0];
  // -- ph0: stage A(t+3); read afB(t)->aN; bar; MFMA rows 0..63 with aC,bC --
  if (STG) {
    u16* sd = &lds[(t + 3) & 3][0][wave * 512];
    const u16* g = gAs + (size_t)(t + 3) * 32;
    GLL16(g, sd);
    GLL16(g + rh, sd + 4096);
  }
#pragma unroll
  for (int m = 0; m < 4; ++m)
    aN[m] = *(const bf16x8*)&aL[(aro + 64 + m * 16) * 32 + col8];
  SBAR();
  __builtin_amdgcn_s_setprio(1);
#pragma unroll
  for (int m = 0; m < 4; ++m)
#pragma unroll
    for (int n = 0; n < 4; ++n)
      acc[m][n] = __builtin_amdgcn_mfma_f32_16x16x32_bf16(aC[m], bC[n], acc[m][n], 0, 0, 0);
  __builtin_amdgcn_s_setprio(0);
  SBAR();
  // -- ph1: stage B(t+3); vmcnt; bar; read tile t+1 frags (aC,bN); MFMA rows 64..127 --
  if (STG) {
    u16* sd = &lds[(t + 3) & 3][1][wave * 512];
    const u16* g = gBs + (size_t)(t + 3) * 32;
    GLL16(g, sd);
    GLL16(g + rh, sd + 4096);
  }
  if (!LAST) asm volatile("s_waitcnt vmcnt(%0)" ::"n"(VM) : "memory");
  SBAR();
  if (!LAST) {
#pragma unroll
    for (int m = 0; m < 4; ++m)
      aC[m] = *(const bf16x8*)&aL1[(aro + m * 16) * 32 + col8];
#pragma unroll
    for (int n = 0; n < 4; ++n)
      bN[n] = *(const bf16x8*)&bL1[(bro + n * 16) * 32 + col8];
    __builtin_amdgcn_sched_barrier(0);  // keep reads issued before the MFMA cluster
  }
  __builtin_amdgcn_s_setprio(1);
#pragma unroll
  for (int m = 0; m < 4; ++m)
#pragma unroll
    for (int n = 0; n < 4; ++n)
      acc[m + 4][n] =
          __builtin_amdgcn_mfma_f32_16x16x32_bf16(aN[m], bC[n], acc[m + 4][n], 0, 0, 0);
  __builtin_amdgcn_s_setprio(0);
  SBAR();
}

__global__ __launch_bounds__(512, 2) void gemm_bt(
    const u16* __restrict__ A, const u16* __restrict__ B,
    float* __restrict__ C, const float* __restrict__ gp,
    int M, int N, int K) {
  __shared__ u16 lds[4][2][8192];  // 4 bufs x (A 256x32 | B 256x32) bf16 = 128 KiB
  const int tid = threadIdx.x;
  const int lane = tid & 63;
  const int wave = tid >> 6;

  // XCD-aware bijective swizzle: nwg = 512 = 8 XCDs x 64, N-major per XCD.
  const int bid = blockIdx.x;
  const int wg = (bid & 7) * 64 + (bid >> 3);
  const int bx = wg >> 5;   // 0..15 (N)
  const int by = wg & 31;   // 0..31 (M)
  const int m0 = by * 256;
  const int n0 = bx * 256;
  const int NK = K >> 5;    // 128 K-tiles of BK=32

  f32x4 zero = {0.0f, 0.0f, 0.0f, 0.0f};
  f32x4 acc[8][4];
#pragma unroll
  for (int i = 0; i < 8; ++i)
#pragma unroll
    for (int j = 0; j < 4; ++j) acc[i][j] = zero;

  const int wrow = wave >> 2;   // wave owns rows [wrow*128, +128)
  const int wcol = wave & 3;    // cols [wcol*64, +64)

  // Staging: linear LDS dest (global_load_lds rule), inverse-swizzled global src.
  const int srow = wave * 16 + (lane >> 2);
  const int scol = (((lane & 3) ^ ((lane >> 3) & 3)) << 3);
  const u16* gAs = A + (size_t)(m0 + srow) * K + scol;
  const u16* gBs = B + (size_t)(n0 + srow) * K + scol;
  const size_t rh = (size_t)128 * K;  // second 128-row half of each chunk

  // Fragment reads: granule (lane>>4) ^ ((row>>1)&3); row bases all == 0 mod 16.
  const int aro = wrow * 128 + (lane & 15);
  const int bro = wcol * 64 + (lane & 15);
  const int col8 = (((lane >> 4) ^ ((lane >> 1) & 3)) << 3);

  // prologue: stage K-tiles 0,1,2 (A0 B0 A1 B1 A2 B2 = 12 loads/wave)
#pragma unroll
  for (int t = 0; t < 3; ++t) {
    u16* dA = &lds[t][0][wave * 512];
    u16* dB = &lds[t][1][wave * 512];
    const u16* ga = gAs + (size_t)t * 32;
    const u16* gb = gBs + (size_t)t * 32;
    GLL16(ga, dA);
    GLL16(ga + rh, dA + 4096);
    GLL16(gb, dB);
    GLL16(gb + rh, dB + 4096);
  }
  asm volatile("s_waitcnt vmcnt(8)" ::: "memory");  // A0,B0 landed
  SBAR();

  // preload tile-0 fragments (one-time exposed LDS wait)
  bf16x8 aC[4], aN[4], bC[4], bN[4];
#pragma unroll
  for (int m = 0; m < 4; ++m)
    aC[m] = *(const bf16x8*)&lds[0][0][(aro + m * 16) * 32 + col8];
#pragma unroll
  for (int n = 0; n < 4; ++n)
    bC[n] = *(const bf16x8*)&lds[0][1][(bro + n * 16) * 32 + col8];

  // B-frags ping-pong (bC/bN roles alternate per tile); A writes back into aC in ph1.
  int t = 0;
  for (; t < NK - 4; t += 2) {
    ktile<8, true, false>(t, lds, gAs, gBs, rh, aro, bro, col8, wave, aC, aN, bC, bN, acc);
    ktile<8, true, false>(t + 1, lds, gAs, gBs, rh, aro, bro, col8, wave, aC, aN, bN, bC, acc);
  }
  ktile<8, true,  false>(t,     lds, gAs, gBs, rh, aro, bro, col8, wave, aC, aN, bC, bN, acc);
  ktile<4, false, false>(t + 1, lds, gAs, gBs, rh, aro, bro, col8, wave, aC, aN, bN, bC, acc);
  ktile<0, false, false>(t + 2, lds, gAs, gBs, rh, aro, bro, col8, wave, aC, aN, bC, bN, acc);
  ktile<0, false, true >(t + 3, lds, gAs, gBs, rh, aro, bro, col8, wave, aC, aN, bN, bC, acc);

  // epilogue: C/D layout col=lane&15, row=(lane>>4)*4+reg (m89/m91-verified)
  const float gs = (*gp) / 2688.0f;
  const int crow = m0 + wrow * 128 + ((lane >> 4) << 2);
  const int ccol = n0 + wcol * 64 + (lane & 15);
#pragma unroll
  for (int m = 0; m < 8; ++m)
#pragma unroll
    for (int r = 0; r < 4; ++r) {
      float* cp = C + (size_t)(crow + m * 16 + r) * N + ccol;
#pragma unroll
      for (int n = 0; n < 4; ++n) cp[n * 16] = acc[m][n][r] * gs;
    }
}

extern "C" void kernel_launch(void* const* d_in, const int* in_sizes, int n_in,
                              void* d_out, int out_size, void* d_ws, size_t ws_size,
                              hipStream_t stream) {
  const float* x   = (const float*)d_in[0];   // (T, I) fp32
  const float* w   = (const float*)d_in[1];   // (O, I) fp32
  const float* pba = (const float*)d_in[2];   // (O, I/16) fp32
  const float* gam = (const float*)d_in[3];   // scalar fp32
  float* out = (float*)d_out;                 // (T, O) fp32

  const int T = 8192, I = 4096, O = 4096;
  u16* xb = (u16*)d_ws;                       // T*I bf16 = 64 MB
  u16* wb = xb + (size_t)T * I;               // O*I bf16 = 32 MB

  long n4 = (long)T * I / 4;                  // 8.4M float4 threads
  hipLaunchKernelGGL(cvt_x_bf16, dim3((unsigned)((n4 + 255) / 256)), dim3(256), 0, stream,
                     x, xb, n4);
  int nth = O * (I / 16) * 4;                 // 4 lanes per 16-elem block
  hipLaunchKernelGGL(dequant_w, dim3(nth / 256), dim3(256), 0, stream,
                     w, pba, gam, wb, nth);
  hipLaunchKernelGGL(gemm_bt, dim3(O / 256 * (T / 256)), dim3(512), 0, stream,
                     xb, wb, out, gam, T, O, I);
}